// Round 8
// baseline (634.642 us; speedup 1.0000x reference)
//
#include <hip/hip_runtime.h>
#include <hip/hip_bf16.h>

// GGNN encoder: N=10000, H=512, T=4, E=40000, L=2 x 2 timesteps.
// fp32 inputs, fp32 output, bf16 MFMA internally.
//
// Per step (2 GEMM dispatches):
//   Msg  = h @ Wmsg_cat^T              (N x 2048, K=512)   [MODE 0]
//   inc  = gather-sum(Msg) + cnt*b     (N x 512)           [gather_msum]
//   h'   = fused GRU GEMM: [inc|h] @ Wrznh^T with GATE-INTERLEAVED packing
//          + split epilogue -> h (bf16)                    [MODE 1]
// Final: FC + column-max fused [MODE 3] -> writeout.
//
// r19 change (single lever): ZERO-barrier GEMM -- one WAVE per 64x64 tile.
//   r14/r18 proved the regime is lockstep-barrier latency (each barrier
//   removal bought 5-12us/dispatch; still ~1700cyc/block-iter vs ~300
//   content). A single-wave block needs NO s_barrier at all: its own
//   vmcnt orders gll16->ds_read; lgkmcnt(0) before the buf overwrite
//   replaces the reuse barrier. This keeps the COALESCED global_load_lds
//   staging (r15's failure was scattered per-lane A loads, 16 lines/instr
//   -- that flaw is absent here). 2x8KB LDS bufs -> ~8-10 independent
//   waves/CU slip freely. Depth-1.5: A(kt+2) issued mid-iter (full iter
//   to land), vmcnt(24) steady / vmcnt(8) tail; B reg ping-pong.
//   Packed weights reinterpret directly: 64-col block bcol -> ct=bcol>>1,
//   wc=bcol&1 (prep unchanged). Gate-interleave: j==gate, hcol=bcol*16+lm.
//
// Carried: fused GRU epilogue (per-kt j-skip), split (a,z)-LDS blend with
// coalesced h reads (r17), no-h32 (r16), XCD-aware swizzle, involutive LDS
// bank swizzle on A staging, BK=64.

#define NN 10000
#define HD 512
#define NT 4
#define NE 40000
#define CAP 24          // max edges per (target,type); P(Poisson(4)>24)~1e-14/bin
#define GR 160          // 64-row panels, padded to multiple of 8 (157 used)

typedef __bf16 bf16x8 __attribute__((ext_vector_type(8)));
typedef float f32x4 __attribute__((ext_vector_type(4)));
union V16 { int4 i; bf16x8 b; };

typedef __attribute__((address_space(1))) const unsigned int gu32;
typedef __attribute__((address_space(3))) unsigned int lu32;
__device__ __forceinline__ void gll16(const void* g, void* l) {
    __builtin_amdgcn_global_load_lds((gu32*)g, (lu32*)l, 16, 0, 0);
}

__device__ __forceinline__ float bfl(__bf16 v) { return (float)v; }

// pack 8 fp32 -> int4 of 8 bf16
__device__ __forceinline__ int4 cvt8(const float* __restrict__ s) {
    float4 v0 = *(const float4*)s, v1 = *(const float4*)(s + 4);
    V16 o;
    o.b[0] = (__bf16)v0.x; o.b[1] = (__bf16)v0.y; o.b[2] = (__bf16)v0.z; o.b[3] = (__bf16)v0.w;
    o.b[4] = (__bf16)v1.x; o.b[5] = (__bf16)v1.y; o.b[6] = (__bf16)v1.z; o.b[7] = (__bf16)v1.w;
    return o.i;
}

// Packed-W layout: [ct][kt32][s], s=0..511: wc=s>>8, j=(s>>6)&3, lane=s&63.
// Entry = int4 of W[pc][kt32*32+quad*8 .. +8], pc = ct*128+wc*64+j*16+(lane&15).
__device__ __forceinline__ void pk_decode(int rem, int KTbits, int& col, int& kk) {
    int ct = rem >> (KTbits + 9);
    int r2 = rem & ((1 << (KTbits + 9)) - 1);
    int kt = r2 >> 9, s = r2 & 511;
    int lane = s & 63;
    col = ct * 128 + ((s >> 8) << 6) + (((s >> 6) & 3) << 4) + (lane & 15);
    kk = kt * 32 + ((lane >> 4) & 3) * 8;
}

// ---------------- fused prep: pack weights, init, bins ----------------------
__global__ void prep_all(const float* __restrict__ Wmsg, const float* __restrict__ Wih,
                         const float* __restrict__ Whh, const float* __restrict__ fcW,
                         const float* __restrict__ x, const int* __restrict__ edges,
                         int4* __restrict__ WmPK, int4* __restrict__ WrznhPK,
                         int4* __restrict__ WfPK,
                         __hip_bfloat16* __restrict__ ab,
                         int* __restrict__ bcnt, int* __restrict__ bins) {
    int blk = blockIdx.x, tid = threadIdx.x;
    if (blk < 1024) {            // WmPK: per layer 16ct x 16kt x 512 = 131072
        int g = blk * 256 + tid;
        int l = g >> 17, rem = g & 131071;
        int col, kk; pk_decode(rem, 4, col, kk);
        WmPK[g] = cvt8(Wmsg + (size_t)l * 1048576 + (size_t)col * 512 + kk);
        return;
    }
    blk -= 1024;
    if (blk < 2048) {            // WrznhPK: per layer 16ct x 32kt x 512 = 262144
        // GATE-INTERLEAVED: packed col pc -> gate g=(pc>>4)&3, hcol=(pc>>6)*16+(pc&15)
        int g = blk * 256 + tid;
        int l = g >> 18, rem = g & 262143;
        int col, kk; pk_decode(rem, 5, col, kk);
        int gate = (col >> 4) & 3;
        int hcol = ((col >> 7) * 2 + ((col >> 6) & 1)) * 16 + (col & 15);
        int4 v = make_int4(0, 0, 0, 0);
        if (kk < 512) {
            // inc-half: W_ih rows {r:hcol, z:512+hcol, i_n:1024+hcol}; hn=0
            if (gate < 3) v = cvt8(Wih + (size_t)l * 786432 + (size_t)(gate * 512 + hcol) * 512 + kk);
        } else {
            // h-half: W_hh rows {r:hcol, z:512+hcol, hn:1024+hcol}; i_n=0
            if (gate < 2) v = cvt8(Whh + (size_t)l * 786432 + (size_t)(gate * 512 + hcol) * 512 + (kk - 512));
            else if (gate == 3) v = cvt8(Whh + (size_t)l * 786432 + (size_t)(1024 + hcol) * 512 + (kk - 512));
        }
        WrznhPK[g] = v;
        return;
    }
    blk -= 2048;
    if (blk < 128) {             // WfPK: 4ct x 16kt x 512 = 32768
        int g = blk * 256 + tid;
        int col, kk; pk_decode(g, 4, col, kk);
        WfPK[g] = cvt8(fcW + (size_t)col * 512 + kk);
        return;
    }
    blk -= 128;
    if (blk < 5000) {            // init: abA h-slot <- bf16(x)
        int i = blk * 1024 + tid * 4;
        float4 v = *(const float4*)(x + i);
        int m = i >> 9, c = i & 511;
        __hip_bfloat16 o[4] = {__float2bfloat16(v.x), __float2bfloat16(v.y),
                               __float2bfloat16(v.z), __float2bfloat16(v.w)};
        *(ulong1*)(ab + (size_t)m * 1024 + 512 + c) = *(ulong1*)o;
        return;
    }
    blk -= 5000;
    {                            // build_bins
        int i = blk * 256 + tid;
        if (i >= NT * NE) return;
        int src = edges[2 * i], tgt = edges[2 * i + 1];
        int t = i / NE;
        int b = tgt * NT + t;
        int pos = atomicAdd(&bcnt[b], 1);
        if (pos < CAP) bins[(size_t)b * CAP + pos] = src;
    }
}

// ---------------- gather: inc[n][c] = sum_t sum_src Msg[src][t*512+c] + cnt*bm
__global__ __launch_bounds__(256) void gather_msum(
    const int* __restrict__ bins, const int* __restrict__ bcnt,
    const float* __restrict__ bm, const __hip_bfloat16* __restrict__ Msg,
    __hip_bfloat16* __restrict__ inc) {
    int wave = threadIdx.x >> 6, lane = threadIdx.x & 63;
    int n = blockIdx.x * 4 + wave;
    int co = lane * 8;
    float acc[8] = {0, 0, 0, 0, 0, 0, 0, 0};
#pragma unroll
    for (int t = 0; t < NT; ++t) {
        int bi = n * NT + t;
        int cnt = bcnt[bi]; if (cnt > CAP) cnt = CAP;
        const int* bl = bins + (size_t)bi * CAP;
        for (int e = 0; e < cnt; ++e) {
            int src = bl[e];
            V16 v; v.i = *(const int4*)(Msg + (size_t)src * 2048 + t * 512 + co);
#pragma unroll
            for (int k = 0; k < 8; ++k) acc[k] += (float)v.b[k];
        }
        float4 b0 = *(const float4*)(bm + t * 512 + co);
        float4 b1 = *(const float4*)(bm + t * 512 + co + 4);
        float fc = (float)cnt;
        acc[0] += fc * b0.x; acc[1] += fc * b0.y; acc[2] += fc * b0.z; acc[3] += fc * b0.w;
        acc[4] += fc * b1.x; acc[5] += fc * b1.y; acc[6] += fc * b1.z; acc[7] += fc * b1.w;
    }
    V16 o;
#pragma unroll
    for (int k = 0; k < 8; ++k) o.b[k] = (__bf16)acc[k];
    *(int4*)(inc + (size_t)n * 1024 + co) = o.i;
}

// ---------------- monotone-uint float max encoding ----------------
__device__ __forceinline__ unsigned fenc(float f) {
    unsigned b = __float_as_uint(f);
    return b ^ (((int)b >> 31) | 0x80000000u);
}
__device__ __forceinline__ float fdec(unsigned u) {
    unsigned b = (u & 0x80000000u) ? (u ^ 0x80000000u) : ~u;
    return __uint_as_float(b);
}

// ---------------- GEMM: out = A(NNxK,lda) @ W^T, ONE WAVE per 64x64 tile ----
// Zero barriers. 2 x 8KB LDS bufs; per iter kt: loadB(kt+1); vmcnt(24)
// [A(kt) staged]; ds_read A frags; lgkmcnt(0); issueA(kt+2 -> buf kt&1);
// MFMA. Tail vmcnt(8). Involutive bank swizzle on staging/read.
template<int MODE>
__global__ __launch_bounds__(64) void gemm(
    const __hip_bfloat16* __restrict__ A, int lda, int K,
    const int4* __restrict__ Wpk,
    const float* __restrict__ b0, const float* __restrict__ b1,
    __hip_bfloat16* __restrict__ obf, int ldo,
    unsigned* __restrict__ om) {
    __shared__ int4 sA4[2][512];              // 16 KB: A staging; epilogue scratch
    __shared__ unsigned sm[64];
    __hip_bfloat16* lt = (__hip_bfloat16*)sA4;    // MODE 0 epilogue view [64][72]
    float2* ldsZ = (float2*)sA4;                  // MODE 1 epilogue view [64][17]

    const int NBC = (MODE == 3) ? 8 : 32;     // 64-col blocks in grid
    int bid = blockIdx.x;
    int xcd = bid & 7, kq = bid >> 3;
    int bcol = kq % NBC;
    int brow = xcd + 8 * (kq / NBC);          // 0..159 exactly covered
    int m0 = brow * 64, n0 = bcol * 64;

    int lane = threadIdx.x;                   // 0..63
    int lm = lane & 15, quad = lane >> 4;
    int qx = (lm >> 1) & 3;                   // read-side bank swizzle

    const int KT32 = K >> 5;
    const int KT = K >> 6;                    // BK64 tiles
    const int kend = KT;
    int ct = bcol >> 1, wcc = bcol & 1;       // reinterpret packed-W for 64-col
    const int4* Wp = Wpk + ((size_t)ct * KT32 << 9) + wcc * 256 + lane;

    // buf = 64 rows x 64 k: two 32-k sub-slabs of 256 int4, bank-swizzled.
    auto issueA = [&](int kt, int p) {
        int k0 = kt << 6;
#pragma unroll
        for (int it = 0; it < 8; ++it) {
            int idx = it * 64 + lane;         // 0..511
            int s = idx >> 8, rem = idx & 255;
            int row = rem >> 2;
            int kc = (rem & 3) ^ ((row >> 1) & 3);    // src-side swizzle
            int gm = m0 + row; gm = gm < NN ? gm : NN - 1;
            gll16(A + (size_t)gm * lda + k0 + s * 32 + kc * 8,
                  (__hip_bfloat16*)(sA4[p]) + idx * 8);
        }
    };
    auto loadB = [&](int kt, int4 (&bb)[2][4]) {
#pragma unroll
        for (int s = 0; s < 2; ++s) {
            const int4* wn = Wp + ((size_t)(2 * kt + s) << 9);
#pragma unroll
            for (int j = 0; j < 4; ++j) bb[s][j] = wn[j * 64];
        }
    };

    f32x4 acc[4][4] = {};
    int4 bb0[2][4], bb1[2][4];
    issueA(0, 0);
    issueA(1, 1);
    loadB(0, bb0);

    auto ktbody = [&](int kt, int4 (&bbCur)[2][4], int4 (&bbNxt)[2][4]) {
        int p = kt & 1;
        if (kt + 1 < kend) loadB(kt + 1, bbNxt);
        __builtin_amdgcn_sched_barrier(0);
        // retire A(kt): FIFO = [A(kt)8, B(kt)8, A(kt+1)8, B(kt+1)8]
        if (kt + 1 < kend) __builtin_amdgcn_s_waitcnt(0x4F78);  // vmcnt(24)
        else               __builtin_amdgcn_s_waitcnt(0x0F78);  // vmcnt(8)
        __builtin_amdgcn_sched_barrier(0);
        V16 a[4][2];
#pragma unroll
        for (int i = 0; i < 4; ++i)
#pragma unroll
            for (int s = 0; s < 2; ++s)
                a[i][s].i = sA4[p][s * 256 + (i * 16 + lm) * 4 + (quad ^ qx)];
        __builtin_amdgcn_s_waitcnt(0xC07F);   // lgkmcnt(0): ds_reads landed
        __builtin_amdgcn_sched_barrier(0);    // pin overwrite below the wait
        if (kt + 2 < kend) issueA(kt + 2, p); // overwrite own buf: safe (1 wave)
#pragma unroll
        for (int s = 0; s < 2; ++s)
#pragma unroll
            for (int i = 0; i < 4; ++i)
#pragma unroll
                for (int j = 0; j < 4; ++j) {
                    if (MODE == 1) {   // structural zeros: i_n no h-half, hn no inc-half
                        if (j == 2 && kt >= 8) continue;
                        if (j == 3 && kt < 8) continue;
                    }
                    V16 b; b.i = bbCur[s][j];
                    acc[i][j] = __builtin_amdgcn_mfma_f32_16x16x32_bf16(a[i][s].b, b.b, acc[i][j], 0, 0, 0);
                }
        __builtin_amdgcn_sched_barrier(0);
    };

    for (int k2 = 0; k2 < kend; k2 += 2) {       // kend always even (8 or 16)
        ktbody(k2, bb0, bb1);
        ktbody(k2 + 1, bb1, bb0);
    }

    if (MODE == 0) {
        // LDS-transpose epilogue: 64x64 bf16 tile, padded stride 72 (16B-aligned)
        __syncthreads();
#pragma unroll
        for (int j = 0; j < 4; ++j)
#pragma unroll
            for (int i = 0; i < 4; ++i)
#pragma unroll
                for (int r = 0; r < 4; ++r)
                    lt[(i * 16 + quad * 4 + r) * 72 + j * 16 + lm] = __float2bfloat16(acc[i][j][r]);
        __syncthreads();
#pragma unroll
        for (int q = 0; q < 8; ++q) {
            int idx = q * 64 + lane;
            int rl = idx >> 3, c8 = (idx & 7) * 8;
            int m = m0 + rl;
            if (m < NN)
                *(int4*)(obf + (size_t)m * ldo + n0 + c8) =
                    *(const int4*)(lt + rl * 72 + c8);
        }
    } else if (MODE == 1) {
        // fused GRU: acc[i][0..3] = r,z,i_n,hn for hcol = bcol*16+lm.
        // Store (a,z)=((1-z)*n, z) to LDS; blend with coalesced h reads.
        __syncthreads();
        int hcol = bcol * 16 + lm;
        float rb = b0[hcol] + b1[hcol];
        float zb = b0[512 + hcol] + b1[512 + hcol];
        float ib = b0[1024 + hcol];
        float hb = b1[1024 + hcol];
#pragma unroll
        for (int i = 0; i < 4; ++i)
#pragma unroll
            for (int r = 0; r < 4; ++r) {
                int rloc = i * 16 + quad * 4 + r;
                float rr = 1.f / (1.f + __expf(-(acc[i][0][r] + rb)));
                float zz = 1.f / (1.f + __expf(-(acc[i][1][r] + zb)));
                float nx = (acc[i][2][r] + ib) + rr * (acc[i][3][r] + hb);
                float n = 1.f - 2.f / (__expf(2.f * nx) + 1.f);
                ldsZ[rloc * 17 + lm] = make_float2((1.f - zz) * n, zz);
            }
        __syncthreads();
        // writeout: 64 rows x 16 hcols bf16; h read 8B/thread (32B/row, L2-hot)
#pragma unroll
        for (int q = 0; q < 4; ++q) {
            int idx = q * 64 + lane;              // 256 4-col units
            int rl = idx >> 2, c4 = (idx & 3) * 4;
            int m = m0 + rl;
            if (m < NN) {
                ulong1 hraw = *(const ulong1*)(A + (size_t)m * lda + 512 + bcol * 16 + c4);
                const __bf16* hb4 = (const __bf16*)&hraw;
                const float2* pz = ldsZ + rl * 17 + c4;
                __hip_bfloat16 ob[4];
#pragma unroll
                for (int e = 0; e < 4; ++e) {
                    float2 az = pz[e];
                    ob[e] = __float2bfloat16(az.x + az.y * bfl(hb4[e]));
                }
                *(ulong1*)(obf + (size_t)m * ldo + bcol * 16 + c4) = *(ulong1*)ob;
            }
        }
    } else {   // MODE 3: FC + column max
        sm[lane] = 0;
        __syncthreads();
#pragma unroll
        for (int j = 0; j < 4; ++j) {
            int c = j * 16 + lm;
            float bias = b0[n0 + c];
            float mx = -INFINITY;
#pragma unroll
            for (int i = 0; i < 4; ++i) {
                int r0 = m0 + i * 16 + quad * 4;
#pragma unroll
                for (int r = 0; r < 4; ++r) {
                    int m = r0 + r;
                    if (m < NN) mx = fmaxf(mx, acc[i][j][r] + bias);
                }
            }
            atomicMax(&sm[c], fenc(mx));
        }
        __syncthreads();
        atomicMax(&om[n0 + lane], sm[lane]);
    }
}

__global__ void writeout(const unsigned* __restrict__ om, float* __restrict__ o) {
    int c = threadIdx.x;
    o[c] = fdec(om[c]);
}

// ---------------- launch ----------------
extern "C" void kernel_launch(void* const* d_in, const int* in_sizes, int n_in,
                              void* d_out, int out_size, void* d_ws, size_t ws_size,
                              hipStream_t stream) {
    (void)in_sizes; (void)n_in; (void)out_size; (void)ws_size;
    const float* x    = (const float*)d_in[0];
    const int*   edges= (const int*)d_in[1];
    const float* Wmsg = (const float*)d_in[2];
    const float* bmsg = (const float*)d_in[3];
    const float* Wih  = (const float*)d_in[4];
    const float* Whh  = (const float*)d_in[5];
    const float* bih  = (const float*)d_in[6];
    const float* bhh  = (const float*)d_in[7];
    const float* fcW  = (const float*)d_in[8];
    const float* fcb  = (const float*)d_in[9];
    float* out = (float*)d_out;

    char* ws = (char*)d_ws;
    size_t off = 0;
    auto alloc = [&](size_t bytes) -> void* {
        void* p = ws + off; off += (bytes + 255) & ~(size_t)255; return p;
    };
    __hip_bfloat16* abA  = (__hip_bfloat16*)alloc((size_t)NN * 1024 * 2);   // 20.5 MB
    __hip_bfloat16* abB  = (__hip_bfloat16*)alloc((size_t)NN * 1024 * 2);   // 20.5 MB
    int*            bcnt = (int*)alloc((size_t)NN * NT * 4);                // 160 KB
    int*            bins = (int*)alloc((size_t)NN * NT * CAP * 4);          // 3.8 MB
    unsigned*       om   = (unsigned*)alloc(HD * 4);
    int4*           WmPK   = (int4*)alloc((size_t)2 * 131072 * 16);         // 4.2 MB
    int4*           WrznhPK= (int4*)alloc((size_t)2 * 262144 * 16);         // 8.4 MB
    int4*           WfPK   = (int4*)alloc((size_t)32768 * 16);              // 0.5 MB
    __hip_bfloat16* Msg  = (__hip_bfloat16*)alloc((size_t)NN * 2048 * 2);   // 41 MB
    // total ~99 MB

    hipMemsetAsync(bcnt, 0, (size_t)NN * NT * 4, stream);
    hipMemsetAsync(om, 0, HD * 4, stream);
    prep_all<<<1024 + 2048 + 128 + 5000 + 625, 256, 0, stream>>>(
        Wmsg, Wih, Whh, fcW, x, edges, WmPK, WrznhPK, WfPK, abA, bcnt, bins);

    for (int s = 0; s < 4; ++s) {
        int layer = s >> 1;
        __hip_bfloat16* cur = (s & 1) ? abB : abA;
        __hip_bfloat16* nxt = (s & 1) ? abA : abB;
        const int4* Wm = WmPK + (size_t)layer * 131072;
        const int4* Wz = WrznhPK + (size_t)layer * 262144;
        const float* bm = bmsg + (size_t)layer * 2048;
        const float* bi = bih + (size_t)layer * 1536;
        const float* bh = bhh + (size_t)layer * 1536;

        // Msg = h @ Wm^T  (out 2048, K=512)
        gemm<0><<<32 * GR, 64, 0, stream>>>(cur + 512, 1024, 512, Wm,
            nullptr, nullptr, Msg, 2048, nullptr);
        // inc = gather(Msg) + cnt*bm -> cur[0:512]
        gather_msum<<<NN / 4, 256, 0, stream>>>(bins, bcnt, bm, Msg, cur);
        // fused GRU GEMM -> nxt h-slot (bf16)
        gemm<1><<<32 * GR, 64, 0, stream>>>(cur, 1024, 1024, Wz,
            bi, bh, nxt + 512, 1024, nullptr);
    }
    // FC + column max (final h in abA h-slot after 4 steps)
    gemm<3><<<8 * GR, 64, 0, stream>>>(abA + 512, 1024, 512, WfPK,
        fcb, nullptr, nullptr, 0, om);
    writeout<<<1, 512, 0, stream>>>(om, out);
}

// Round 9
// 622.555 us; speedup vs baseline: 1.0194x; 1.0194x over previous
//
#include <hip/hip_runtime.h>
#include <hip/hip_bf16.h>

// GGNN encoder: N=10000, H=512, T=4, E=40000, L=2 x 2 timesteps.
// fp32 inputs, fp32 output, bf16 MFMA internally.
//
// Per step (2 GEMM dispatches):
//   Msg  = h @ Wmsg_cat^T              (N x 2048, K=512)   [MODE 0]
//   inc  = gather-sum(Msg) + cnt*b     (N x 512)           [gather_msum]
//   h'   = fused GRU GEMM: [inc|h] @ Wrznh^T with GATE-INTERLEAVED packing
//          + split epilogue -> h (bf16)                    [MODE 1]
// Final: FC + column-max fused [MODE 3] -> writeout.
//
// r20: REVERT r19 (1-wave blocks doubled per-wave staging work; -17%).
//   Back to r18 (128x128 tile, 4 waves, ONE barrier/iter, 3x16KB A bufs),
//   plus ONE lever: B prefetch depth 2 -> 3.
//   Theory: the XCD swizzle partitions ROWS per XCD, so every XCD reads all
//   16 bcols of packed W (4.2MB) -> W thrashes the 4MB per-XCD L2 and B
//   loads come from L3 (~500-700cy). B's old ping-pong gave only ONE iter
//   (~300-600cy) of slack -> part of an L3 latency exposed EVERY iteration,
//   amplified x4 by the barrier (~2400cy/block-iter vs ~300 content).
//   Three named B register sets (no runtime indexing -> no scratch),
//   3-unrolled rotation; per iter issue [B(kt+2) x8] at top, A(kt+2)
//   post-barrier. FIFO ladder: steady vmcnt(20) (retires through A(kt));
//   tails vmcnt(12) @kend-2, vmcnt(0) @kend-1.
//
// Carried: fused GRU epilogue (gate-interleaved WrznhPK, per-kt j-skip),
// split (a,z)-LDS blend with coalesced h reads (r17), no-h32 (r16),
// XCD-aware swizzle, involutive LDS bank swizzle on A staging, BK=64,
// one barrier per K-iter (r18).

#define NN 10000
#define HD 512
#define NT 4
#define NE 40000
#define CAP 24          // max edges per (target,type); P(Poisson(4)>24)~1e-14/bin
#define GYROWS 80       // padded to multiple of 8 for XCD swizzle (79 used)

typedef __bf16 bf16x8 __attribute__((ext_vector_type(8)));
typedef float f32x4 __attribute__((ext_vector_type(4)));
union V16 { int4 i; bf16x8 b; };

typedef __attribute__((address_space(1))) const unsigned int gu32;
typedef __attribute__((address_space(3))) unsigned int lu32;
__device__ __forceinline__ void gll16(const void* g, void* l) {
    __builtin_amdgcn_global_load_lds((gu32*)g, (lu32*)l, 16, 0, 0);
}

__device__ __forceinline__ float bfl(__bf16 v) { return (float)v; }

// pack 8 fp32 -> int4 of 8 bf16
__device__ __forceinline__ int4 cvt8(const float* __restrict__ s) {
    float4 v0 = *(const float4*)s, v1 = *(const float4*)(s + 4);
    V16 o;
    o.b[0] = (__bf16)v0.x; o.b[1] = (__bf16)v0.y; o.b[2] = (__bf16)v0.z; o.b[3] = (__bf16)v0.w;
    o.b[4] = (__bf16)v1.x; o.b[5] = (__bf16)v1.y; o.b[6] = (__bf16)v1.z; o.b[7] = (__bf16)v1.w;
    return o.i;
}

// Packed-W layout: [ct][kt32][s], s=0..511: wc=s>>8, j=(s>>6)&3, lane=s&63.
// Entry = int4 of W[pc][kt32*32+quad*8 .. +8], pc = ct*128+wc*64+j*16+(lane&15).
__device__ __forceinline__ void pk_decode(int rem, int KTbits, int& col, int& kk) {
    int ct = rem >> (KTbits + 9);
    int r2 = rem & ((1 << (KTbits + 9)) - 1);
    int kt = r2 >> 9, s = r2 & 511;
    int lane = s & 63;
    col = ct * 128 + ((s >> 8) << 6) + (((s >> 6) & 3) << 4) + (lane & 15);
    kk = kt * 32 + ((lane >> 4) & 3) * 8;
}

// ---------------- fused prep: pack weights, init, bins ----------------------
__global__ void prep_all(const float* __restrict__ Wmsg, const float* __restrict__ Wih,
                         const float* __restrict__ Whh, const float* __restrict__ fcW,
                         const float* __restrict__ x, const int* __restrict__ edges,
                         int4* __restrict__ WmPK, int4* __restrict__ WrznhPK,
                         int4* __restrict__ WfPK,
                         __hip_bfloat16* __restrict__ ab,
                         int* __restrict__ bcnt, int* __restrict__ bins) {
    int blk = blockIdx.x, tid = threadIdx.x;
    if (blk < 1024) {            // WmPK: per layer 16ct x 16kt x 512 = 131072
        int g = blk * 256 + tid;
        int l = g >> 17, rem = g & 131071;
        int col, kk; pk_decode(rem, 4, col, kk);
        WmPK[g] = cvt8(Wmsg + (size_t)l * 1048576 + (size_t)col * 512 + kk);
        return;
    }
    blk -= 1024;
    if (blk < 2048) {            // WrznhPK: per layer 16ct x 32kt x 512 = 262144
        // GATE-INTERLEAVED: packed col pc -> gate g=(pc>>4)&3,
        // hcol = (bcol*2 + wc)*16 + lm, bcol=pc>>7, wc=(pc>>6)&1, lm=pc&15.
        int g = blk * 256 + tid;
        int l = g >> 18, rem = g & 262143;
        int col, kk; pk_decode(rem, 5, col, kk);
        int gate = (col >> 4) & 3;
        int hcol = ((col >> 7) * 2 + ((col >> 6) & 1)) * 16 + (col & 15);
        int4 v = make_int4(0, 0, 0, 0);
        if (kk < 512) {
            // inc-half: W_ih rows {r:hcol, z:512+hcol, i_n:1024+hcol}; hn=0
            if (gate < 3) v = cvt8(Wih + (size_t)l * 786432 + (size_t)(gate * 512 + hcol) * 512 + kk);
        } else {
            // h-half: W_hh rows {r:hcol, z:512+hcol, hn:1024+hcol}; i_n=0
            if (gate < 2) v = cvt8(Whh + (size_t)l * 786432 + (size_t)(gate * 512 + hcol) * 512 + (kk - 512));
            else if (gate == 3) v = cvt8(Whh + (size_t)l * 786432 + (size_t)(1024 + hcol) * 512 + (kk - 512));
        }
        WrznhPK[g] = v;
        return;
    }
    blk -= 2048;
    if (blk < 128) {             // WfPK: 4ct x 16kt x 512 = 32768
        int g = blk * 256 + tid;
        int col, kk; pk_decode(g, 4, col, kk);
        WfPK[g] = cvt8(fcW + (size_t)col * 512 + kk);
        return;
    }
    blk -= 128;
    if (blk < 5000) {            // init: abA h-slot <- bf16(x)
        int i = blk * 1024 + tid * 4;
        float4 v = *(const float4*)(x + i);
        int m = i >> 9, c = i & 511;
        __hip_bfloat16 o[4] = {__float2bfloat16(v.x), __float2bfloat16(v.y),
                               __float2bfloat16(v.z), __float2bfloat16(v.w)};
        *(ulong1*)(ab + (size_t)m * 1024 + 512 + c) = *(ulong1*)o;
        return;
    }
    blk -= 5000;
    {                            // build_bins
        int i = blk * 256 + tid;
        if (i >= NT * NE) return;
        int src = edges[2 * i], tgt = edges[2 * i + 1];
        int t = i / NE;
        int b = tgt * NT + t;
        int pos = atomicAdd(&bcnt[b], 1);
        if (pos < CAP) bins[(size_t)b * CAP + pos] = src;
    }
}

// ---------------- gather: inc[n][c] = sum_t sum_src Msg[src][t*512+c] + cnt*bm
__global__ __launch_bounds__(256) void gather_msum(
    const int* __restrict__ bins, const int* __restrict__ bcnt,
    const float* __restrict__ bm, const __hip_bfloat16* __restrict__ Msg,
    __hip_bfloat16* __restrict__ inc) {
    int wave = threadIdx.x >> 6, lane = threadIdx.x & 63;
    int n = blockIdx.x * 4 + wave;
    int co = lane * 8;
    float acc[8] = {0, 0, 0, 0, 0, 0, 0, 0};
#pragma unroll
    for (int t = 0; t < NT; ++t) {
        int bi = n * NT + t;
        int cnt = bcnt[bi]; if (cnt > CAP) cnt = CAP;
        const int* bl = bins + (size_t)bi * CAP;
        for (int e = 0; e < cnt; ++e) {
            int src = bl[e];
            V16 v; v.i = *(const int4*)(Msg + (size_t)src * 2048 + t * 512 + co);
#pragma unroll
            for (int k = 0; k < 8; ++k) acc[k] += (float)v.b[k];
        }
        float4 b0 = *(const float4*)(bm + t * 512 + co);
        float4 b1 = *(const float4*)(bm + t * 512 + co + 4);
        float fc = (float)cnt;
        acc[0] += fc * b0.x; acc[1] += fc * b0.y; acc[2] += fc * b0.z; acc[3] += fc * b0.w;
        acc[4] += fc * b1.x; acc[5] += fc * b1.y; acc[6] += fc * b1.z; acc[7] += fc * b1.w;
    }
    V16 o;
#pragma unroll
    for (int k = 0; k < 8; ++k) o.b[k] = (__bf16)acc[k];
    *(int4*)(inc + (size_t)n * 1024 + co) = o.i;
}

// ---------------- monotone-uint float max encoding ----------------
__device__ __forceinline__ unsigned fenc(float f) {
    unsigned b = __float_as_uint(f);
    return b ^ (((int)b >> 31) | 0x80000000u);
}
__device__ __forceinline__ float fdec(unsigned u) {
    unsigned b = (u & 0x80000000u) ? (u ^ 0x80000000u) : ~u;
    return __uint_as_float(b);
}

// ---------------- GEMM: out = A(NNxK,lda) @ W^T, 128x128 tile, BK=64 ---------
// ONE barrier per K-iter; depth-2 A (3 x 16KB LDS bufs, gll16), depth-3 B
// (three named reg sets, 2 full iters of slack to cover L3 latency).
// Per iter kt: loadB(kt+2); vmcnt(20); s_barrier; ds_read A(kt);
// issueA(kt+2) (post-barrier = race-free); MFMA with B(kt).
// Tails: vmcnt(12) @kend-2, vmcnt(0) @kend-1.
template<int MODE>
__global__ __launch_bounds__(256) void gemm(
    const __hip_bfloat16* __restrict__ A, int lda, int K,
    const int4* __restrict__ Wpk,
    const float* __restrict__ b0, const float* __restrict__ b1,
    __hip_bfloat16* __restrict__ obf, int ldo,
    unsigned* __restrict__ om) {
    __shared__ int4 sA4[3][1024];             // 48 KB: A staging; epilogue scratch
    __shared__ unsigned sm[128];
    __hip_bfloat16* lds = (__hip_bfloat16*)sA4;   // MODE 0 epilogue view
    float2* ldsZ = (float2*)sA4;                  // MODE 1 epilogue view (a,z)

    const int NB = (MODE == 3) ? 4 : 16;      // bcols in grid
    int bid = blockIdx.x;
    int xcd = bid & 7, kq = bid >> 3;
    int bcol = kq % NB;
    int brow = xcd + 8 * (kq / NB);           // 0..79 exactly covered
    int m0 = brow * 128, n0 = bcol * 128;

    int tid = threadIdx.x;
    int lane = tid & 63, wave = tid >> 6;
    int wr = wave >> 1, wc = wave & 1;
    int lm = lane & 15, quad = lane >> 4;
    int qx = (lm >> 1) & 3;                   // read-side bank swizzle

    const int KT32 = K >> 5;
    const int KT = K >> 6;       // BK64 tiles
    const int kend = KT;         // uniform (MODE 1 zero-structure handled per-j)
    const int4* Wp = Wpk + ((size_t)bcol * KT32 << 9) + wc * 256 + lane;

    // LDS per tile = two 32-k sub-slabs of 512 int4; bank-swizzled placement.
    auto issueA = [&](int kt, int p) {
        int k0 = kt << 6;
#pragma unroll
        for (int it = 0; it < 4; ++it) {
            int idx = it * 256 + tid;
            int s = idx >> 9, rem = idx & 511;
            int row = rem >> 2;
            int kc = (rem & 3) ^ ((row >> 1) & 3);    // src-side swizzle
            int gm = m0 + row; gm = gm < NN ? gm : NN - 1;
            gll16(A + (size_t)gm * lda + k0 + s * 32 + kc * 8,
                  (__hip_bfloat16*)(sA4[p]) + idx * 8);
        }
    };
    auto loadB = [&](int kt, int4 (&bb)[2][4]) {
#pragma unroll
        for (int s = 0; s < 2; ++s) {
            const int4* wn = Wp + ((size_t)(2 * kt + s) << 9);
#pragma unroll
            for (int j = 0; j < 4; ++j) bb[s][j] = wn[j * 64];
        }
    };

    f32x4 acc[4][4] = {};
    int4 bb0[2][4], bb1[2][4], bb2[2][4];
    issueA(0, 0);
    issueA(1, 1);
    loadB(0, bb0);
    if (1 < kend) loadB(1, bb1);

    auto ktbody = [&](int kt, int4 (&bbCur)[2][4], int4 (&bbN2)[2][4]) {
        int p = kt % 3;
        if (kt + 2 < kend) loadB(kt + 2, bbN2);   // 2 iters of slack
        __builtin_amdgcn_sched_barrier(0);
        if (kt + 2 < kend)      __builtin_amdgcn_s_waitcnt(0x4F74);  // vmcnt(20)
        else if (kt + 1 < kend) __builtin_amdgcn_s_waitcnt(0x0F7C);  // vmcnt(12)
        else                    __builtin_amdgcn_s_waitcnt(0x0F70);  // vmcnt(0)
        __builtin_amdgcn_s_barrier();   // tile kt staged; all reads of buf
                                        // (kt-1)%3 complete (consumed pre-barrier)
        __builtin_amdgcn_sched_barrier(0);   // pins issueA below the barrier
        V16 a[4][2];
#pragma unroll
        for (int i = 0; i < 4; ++i)
#pragma unroll
            for (int s = 0; s < 2; ++s)
                a[i][s].i = sA4[p][s * 512 + (wr * 64 + i * 16 + lm) * 4 + (quad ^ qx)];
        if (kt + 2 < kend) issueA(kt + 2, (kt + 2) % 3);  // overwrites (kt-1)%3: safe
#pragma unroll
        for (int s = 0; s < 2; ++s)
#pragma unroll
            for (int i = 0; i < 4; ++i)
#pragma unroll
                for (int j = 0; j < 4; ++j) {
                    if (MODE == 1) {   // structural zeros: i_n no h-half, hn no inc-half
                        if (j == 2 && kt >= 8) continue;
                        if (j == 3 && kt < 8) continue;
                    }
                    V16 b; b.i = bbCur[s][j];
                    acc[i][j] = __builtin_amdgcn_mfma_f32_16x16x32_bf16(a[i][s].b, b.b, acc[i][j], 0, 0, 0);
                }
        __builtin_amdgcn_sched_barrier(0);
    };

    int kt = 0;
    while (kt + 3 <= kend) {                 // kend = 8 or 16
        ktbody(kt,     bb0, bb2);
        ktbody(kt + 1, bb1, bb0);
        ktbody(kt + 2, bb2, bb1);
        kt += 3;
    }
    if (kend - kt >= 1) ktbody(kt,     bb0, bb2);
    if (kend - kt >= 2) ktbody(kt + 1, bb1, bb0);

    if (MODE == 0) {
        // LDS-transpose epilogue, 2 row-phases of 64x128 bf16 (coalesced stores)
        __syncthreads();   // acc final; sA4 reusable as scratch
#pragma unroll
        for (int ph = 0; ph < 2; ++ph) {
            if (wr == ph) {
#pragma unroll
                for (int j = 0; j < 4; ++j) {
                    int c = wc * 64 + j * 16 + lm;
#pragma unroll
                    for (int i = 0; i < 4; ++i)
#pragma unroll
                        for (int r = 0; r < 4; ++r)
                            lds[(i * 16 + quad * 4 + r) * 128 + c] = __float2bfloat16(acc[i][j][r]);
                }
            }
            __syncthreads();
#pragma unroll
            for (int q = 0; q < 4; ++q) {
                int idx = q * 256 + tid;
                int rl = idx >> 4, c16 = idx & 15;
                int m = m0 + ph * 64 + rl;
                if (m < NN)
                    *(int4*)(obf + (size_t)m * ldo + n0 + c16 * 8) =
                        *(const int4*)(lds + rl * 128 + c16 * 8);
            }
            __syncthreads();
        }
    } else if (MODE == 1) {
        // fused GRU, split blend: epilogue computes a=(1-z)*n and z (fp32),
        // stores (a,z) pairs to LDS; writeout phase blends with COALESCED
        // bf16 h loads from the A operand's h-half. Same rounding as r16.
        __syncthreads();   // acc final; sA4 reusable as scratch
        int c32 = wc * 16 + lm;
        int hcol = bcol * 32 + c32;
        float rb = b0[hcol] + b1[hcol];
        float zb = b0[512 + hcol] + b1[512 + hcol];
        float ib = b0[1024 + hcol];
        float hb = b1[1024 + hcol];
#pragma unroll
        for (int i = 0; i < 4; ++i)
#pragma unroll
            for (int r = 0; r < 4; ++r) {
                int rloc = wr * 64 + i * 16 + quad * 4 + r;
                float rr = 1.f / (1.f + __expf(-(acc[i][0][r] + rb)));
                float zz = 1.f / (1.f + __expf(-(acc[i][1][r] + zb)));
                float nx = (acc[i][2][r] + ib) + rr * (acc[i][3][r] + hb);
                float n = 1.f - 2.f / (__expf(2.f * nx) + 1.f);
                ldsZ[rloc * 34 + c32] = make_float2((1.f - zz) * n, zz);
            }
        __syncthreads();
        // coalesced writeout: 128 rows x 32 cols bf16 (next step's A h-slot);
        // h read 8B/thread from A[m][512+bcol*32+c4..] (64B per 8 threads).
#pragma unroll
        for (int q = 0; q < 4; ++q) {
            int idx = q * 256 + tid;              // 1024 4-col units
            int rl = idx >> 3, c4 = (idx & 7) * 4;
            int m = m0 + rl;
            if (m < NN) {
                ulong1 hraw = *(const ulong1*)(A + (size_t)m * lda + 512 + bcol * 32 + c4);
                const __bf16* hb4 = (const __bf16*)&hraw;
                const float2* pz = ldsZ + rl * 34 + c4;
                __hip_bfloat16 ob[4];
#pragma unroll
                for (int e = 0; e < 4; ++e) {
                    float2 az = pz[e];
                    ob[e] = __float2bfloat16(az.x + az.y * bfl(hb4[e]));
                }
                *(ulong1*)(obf + (size_t)m * ldo + bcol * 32 + c4) = *(ulong1*)ob;
            }
        }
    } else {   // MODE 3: FC + column max
        if (tid < 128) sm[tid] = 0;
        __syncthreads();
#pragma unroll
        for (int j = 0; j < 4; ++j) {
            int c = wc * 64 + j * 16 + lm;
            float bias = b0[n0 + c];
            float mx = -INFINITY;
#pragma unroll
            for (int i = 0; i < 4; ++i) {
                int r0 = m0 + wr * 64 + i * 16 + quad * 4;
#pragma unroll
                for (int r = 0; r < 4; ++r) {
                    int m = r0 + r;
                    if (m < NN) mx = fmaxf(mx, acc[i][j][r] + bias);
                }
            }
            atomicMax(&sm[c], fenc(mx));
        }
        __syncthreads();
        if (tid < 128) atomicMax(&om[n0 + tid], sm[tid]);
    }
}

__global__ void writeout(const unsigned* __restrict__ om, float* __restrict__ o) {
    int c = threadIdx.x;
    o[c] = fdec(om[c]);
}

// ---------------- launch ----------------
extern "C" void kernel_launch(void* const* d_in, const int* in_sizes, int n_in,
                              void* d_out, int out_size, void* d_ws, size_t ws_size,
                              hipStream_t stream) {
    (void)in_sizes; (void)n_in; (void)out_size; (void)ws_size;
    const float* x    = (const float*)d_in[0];
    const int*   edges= (const int*)d_in[1];
    const float* Wmsg = (const float*)d_in[2];
    const float* bmsg = (const float*)d_in[3];
    const float* Wih  = (const float*)d_in[4];
    const float* Whh  = (const float*)d_in[5];
    const float* bih  = (const float*)d_in[6];
    const float* bhh  = (const float*)d_in[7];
    const float* fcW  = (const float*)d_in[8];
    const float* fcb  = (const float*)d_in[9];
    float* out = (float*)d_out;

    char* ws = (char*)d_ws;
    size_t off = 0;
    auto alloc = [&](size_t bytes) -> void* {
        void* p = ws + off; off += (bytes + 255) & ~(size_t)255; return p;
    };
    __hip_bfloat16* abA  = (__hip_bfloat16*)alloc((size_t)NN * 1024 * 2);   // 20.5 MB
    __hip_bfloat16* abB  = (__hip_bfloat16*)alloc((size_t)NN * 1024 * 2);   // 20.5 MB
    int*            bcnt = (int*)alloc((size_t)NN * NT * 4);                // 160 KB
    int*            bins = (int*)alloc((size_t)NN * NT * CAP * 4);          // 3.8 MB
    unsigned*       om   = (unsigned*)alloc(HD * 4);
    int4*           WmPK   = (int4*)alloc((size_t)2 * 131072 * 16);         // 4.2 MB
    int4*           WrznhPK= (int4*)alloc((size_t)2 * 262144 * 16);         // 8.4 MB
    int4*           WfPK   = (int4*)alloc((size_t)32768 * 16);              // 0.5 MB
    __hip_bfloat16* Msg  = (__hip_bfloat16*)alloc((size_t)NN * 2048 * 2);   // 41 MB
    // total ~99 MB

    hipMemsetAsync(bcnt, 0, (size_t)NN * NT * 4, stream);
    hipMemsetAsync(om, 0, HD * 4, stream);
    prep_all<<<1024 + 2048 + 128 + 5000 + 625, 256, 0, stream>>>(
        Wmsg, Wih, Whh, fcW, x, edges, WmPK, WrznhPK, WfPK, abA, bcnt, bins);

    for (int s = 0; s < 4; ++s) {
        int layer = s >> 1;
        __hip_bfloat16* cur = (s & 1) ? abB : abA;
        __hip_bfloat16* nxt = (s & 1) ? abA : abB;
        const int4* Wm = WmPK + (size_t)layer * 131072;
        const int4* Wz = WrznhPK + (size_t)layer * 262144;
        const float* bm = bmsg + (size_t)layer * 2048;
        const float* bi = bih + (size_t)layer * 1536;
        const float* bh = bhh + (size_t)layer * 1536;

        // Msg = h @ Wm^T  (out 2048, K=512)
        gemm<0><<<16 * GYROWS, 256, 0, stream>>>(cur + 512, 1024, 512, Wm,
            nullptr, nullptr, Msg, 2048, nullptr);
        // inc = gather(Msg) + cnt*bm -> cur[0:512]
        gather_msum<<<NN / 4, 256, 0, stream>>>(bins, bcnt, bm, Msg, cur);
        // fused GRU GEMM -> nxt h-slot (bf16)
        gemm<1><<<16 * GYROWS, 256, 0, stream>>>(cur, 1024, 1024, Wz,
            bi, bh, nxt + 512, 1024, nullptr);
    }
    // FC + column max (final h in abA h-slot after 4 steps)
    gemm<3><<<4 * GYROWS, 256, 0, stream>>>(abA + 512, 1024, 512, WfPK,
        fcb, nullptr, nullptr, 0, om);
    writeout<<<1, 512, 0, stream>>>(om, out);
}

// Round 10
// 589.482 us; speedup vs baseline: 1.0766x; 1.0561x over previous
//
#include <hip/hip_runtime.h>
#include <hip/hip_bf16.h>

// GGNN encoder: N=10000, H=512, T=4, E=40000, L=2 x 2 timesteps.
// fp32 inputs, fp32 output, bf16 MFMA internally.
//
// Per step (2 GEMM dispatches):
//   Msg  = h @ Wmsg_cat^T              (N x 2048, K=512)   [MODE 0]
//   inc  = gather-sum(Msg) + cnt*b     (N x 512)           [gather_msum]
//   h'   = fused GRU GEMM: [inc|h] @ Wrznh^T with GATE-INTERLEAVED packing
//          + split epilogue -> h (bf16)                    [MODE 1]
// Final: FC + column-max fused [MODE 3] -> writeout.
//
// r21: REVERT r20 (B depth-3 was null -> B LATENCY falsified) back to r18,
//   plus ONE lever: bcol-per-XCD swizzle (W becomes L2-resident).
//   Theory: B traffic = 1280 blk x 16 it x 32KB = 655 MB/dispatch. Old
//   swizzle partitioned ROWS per XCD -> every XCD needed all 16 bcols of W
//   (4MB) + streaming A -> W missed the 4MB per-XCD L2 and B came from
//   L3 (~8 B/cyc/CU -> ~40us), matching the 58us-vs-15us-content gap.
//   (Consistent: barrier removals helped ~10% each, depth-3 null, HBM idle
//   -- L3 traffic is invisible to FETCH_SIZE.)
//   New mapping: each XCD owns 2 bcols x all 80 row-panels -> W/XCD =
//   512KB L2-pinned; a panel's two bcols are adjacent bids -> A read once
//   per XCD from L3 (164MB -> ~9us) with x2 L2 reuse. MODE 3: 2 XCDs per
//   bcol, rows split by parity.
//
// Carried (r18 structure): fused GRU epilogue (gate-interleaved WrznhPK,
// per-kt j-skip), split (a,z)-LDS blend with coalesced h reads (r17),
// no-h32 (r16), involutive LDS bank swizzle on A staging, BK=64, 3
// rotating 16KB LDS bufs, depth-2 ping-pong B regs, ONE barrier per K-iter
// (post-barrier issueA), vmcnt(20)/vmcnt(8) ladder.

#define NN 10000
#define HD 512
#define NT 4
#define NE 40000
#define CAP 24          // max edges per (target,type); P(Poisson(4)>24)~1e-14/bin
#define GYROWS 80       // padded to multiple of 8 for XCD swizzle (79 used)

typedef __bf16 bf16x8 __attribute__((ext_vector_type(8)));
typedef float f32x4 __attribute__((ext_vector_type(4)));
union V16 { int4 i; bf16x8 b; };

typedef __attribute__((address_space(1))) const unsigned int gu32;
typedef __attribute__((address_space(3))) unsigned int lu32;
__device__ __forceinline__ void gll16(const void* g, void* l) {
    __builtin_amdgcn_global_load_lds((gu32*)g, (lu32*)l, 16, 0, 0);
}

__device__ __forceinline__ float bfl(__bf16 v) { return (float)v; }

// pack 8 fp32 -> int4 of 8 bf16
__device__ __forceinline__ int4 cvt8(const float* __restrict__ s) {
    float4 v0 = *(const float4*)s, v1 = *(const float4*)(s + 4);
    V16 o;
    o.b[0] = (__bf16)v0.x; o.b[1] = (__bf16)v0.y; o.b[2] = (__bf16)v0.z; o.b[3] = (__bf16)v0.w;
    o.b[4] = (__bf16)v1.x; o.b[5] = (__bf16)v1.y; o.b[6] = (__bf16)v1.z; o.b[7] = (__bf16)v1.w;
    return o.i;
}

// Packed-W layout: [ct][kt32][s], s=0..511: wc=s>>8, j=(s>>6)&3, lane=s&63.
// Entry = int4 of W[pc][kt32*32+quad*8 .. +8], pc = ct*128+wc*64+j*16+(lane&15).
__device__ __forceinline__ void pk_decode(int rem, int KTbits, int& col, int& kk) {
    int ct = rem >> (KTbits + 9);
    int r2 = rem & ((1 << (KTbits + 9)) - 1);
    int kt = r2 >> 9, s = r2 & 511;
    int lane = s & 63;
    col = ct * 128 + ((s >> 8) << 6) + (((s >> 6) & 3) << 4) + (lane & 15);
    kk = kt * 32 + ((lane >> 4) & 3) * 8;
}

// ---------------- fused prep: pack weights, init, bins ----------------------
__global__ void prep_all(const float* __restrict__ Wmsg, const float* __restrict__ Wih,
                         const float* __restrict__ Whh, const float* __restrict__ fcW,
                         const float* __restrict__ x, const int* __restrict__ edges,
                         int4* __restrict__ WmPK, int4* __restrict__ WrznhPK,
                         int4* __restrict__ WfPK,
                         __hip_bfloat16* __restrict__ ab,
                         int* __restrict__ bcnt, int* __restrict__ bins) {
    int blk = blockIdx.x, tid = threadIdx.x;
    if (blk < 1024) {            // WmPK: per layer 16ct x 16kt x 512 = 131072
        int g = blk * 256 + tid;
        int l = g >> 17, rem = g & 131071;
        int col, kk; pk_decode(rem, 4, col, kk);
        WmPK[g] = cvt8(Wmsg + (size_t)l * 1048576 + (size_t)col * 512 + kk);
        return;
    }
    blk -= 1024;
    if (blk < 2048) {            // WrznhPK: per layer 16ct x 32kt x 512 = 262144
        // GATE-INTERLEAVED: packed col pc -> gate g=(pc>>4)&3,
        // hcol = (bcol*2 + wc)*16 + lm, bcol=pc>>7, wc=(pc>>6)&1, lm=pc&15.
        int g = blk * 256 + tid;
        int l = g >> 18, rem = g & 262143;
        int col, kk; pk_decode(rem, 5, col, kk);
        int gate = (col >> 4) & 3;
        int hcol = ((col >> 7) * 2 + ((col >> 6) & 1)) * 16 + (col & 15);
        int4 v = make_int4(0, 0, 0, 0);
        if (kk < 512) {
            // inc-half: W_ih rows {r:hcol, z:512+hcol, i_n:1024+hcol}; hn=0
            if (gate < 3) v = cvt8(Wih + (size_t)l * 786432 + (size_t)(gate * 512 + hcol) * 512 + kk);
        } else {
            // h-half: W_hh rows {r:hcol, z:512+hcol, hn:1024+hcol}; i_n=0
            if (gate < 2) v = cvt8(Whh + (size_t)l * 786432 + (size_t)(gate * 512 + hcol) * 512 + (kk - 512));
            else if (gate == 3) v = cvt8(Whh + (size_t)l * 786432 + (size_t)(1024 + hcol) * 512 + (kk - 512));
        }
        WrznhPK[g] = v;
        return;
    }
    blk -= 2048;
    if (blk < 128) {             // WfPK: 4ct x 16kt x 512 = 32768
        int g = blk * 256 + tid;
        int col, kk; pk_decode(g, 4, col, kk);
        WfPK[g] = cvt8(fcW + (size_t)col * 512 + kk);
        return;
    }
    blk -= 128;
    if (blk < 5000) {            // init: abA h-slot <- bf16(x)
        int i = blk * 1024 + tid * 4;
        float4 v = *(const float4*)(x + i);
        int m = i >> 9, c = i & 511;
        __hip_bfloat16 o[4] = {__float2bfloat16(v.x), __float2bfloat16(v.y),
                               __float2bfloat16(v.z), __float2bfloat16(v.w)};
        *(ulong1*)(ab + (size_t)m * 1024 + 512 + c) = *(ulong1*)o;
        return;
    }
    blk -= 5000;
    {                            // build_bins
        int i = blk * 256 + tid;
        if (i >= NT * NE) return;
        int src = edges[2 * i], tgt = edges[2 * i + 1];
        int t = i / NE;
        int b = tgt * NT + t;
        int pos = atomicAdd(&bcnt[b], 1);
        if (pos < CAP) bins[(size_t)b * CAP + pos] = src;
    }
}

// ---------------- gather: inc[n][c] = sum_t sum_src Msg[src][t*512+c] + cnt*bm
__global__ __launch_bounds__(256) void gather_msum(
    const int* __restrict__ bins, const int* __restrict__ bcnt,
    const float* __restrict__ bm, const __hip_bfloat16* __restrict__ Msg,
    __hip_bfloat16* __restrict__ inc) {
    int wave = threadIdx.x >> 6, lane = threadIdx.x & 63;
    int n = blockIdx.x * 4 + wave;
    int co = lane * 8;
    float acc[8] = {0, 0, 0, 0, 0, 0, 0, 0};
#pragma unroll
    for (int t = 0; t < NT; ++t) {
        int bi = n * NT + t;
        int cnt = bcnt[bi]; if (cnt > CAP) cnt = CAP;
        const int* bl = bins + (size_t)bi * CAP;
        for (int e = 0; e < cnt; ++e) {
            int src = bl[e];
            V16 v; v.i = *(const int4*)(Msg + (size_t)src * 2048 + t * 512 + co);
#pragma unroll
            for (int k = 0; k < 8; ++k) acc[k] += (float)v.b[k];
        }
        float4 b0 = *(const float4*)(bm + t * 512 + co);
        float4 b1 = *(const float4*)(bm + t * 512 + co + 4);
        float fc = (float)cnt;
        acc[0] += fc * b0.x; acc[1] += fc * b0.y; acc[2] += fc * b0.z; acc[3] += fc * b0.w;
        acc[4] += fc * b1.x; acc[5] += fc * b1.y; acc[6] += fc * b1.z; acc[7] += fc * b1.w;
    }
    V16 o;
#pragma unroll
    for (int k = 0; k < 8; ++k) o.b[k] = (__bf16)acc[k];
    *(int4*)(inc + (size_t)n * 1024 + co) = o.i;
}

// ---------------- monotone-uint float max encoding ----------------
__device__ __forceinline__ unsigned fenc(float f) {
    unsigned b = __float_as_uint(f);
    return b ^ (((int)b >> 31) | 0x80000000u);
}
__device__ __forceinline__ float fdec(unsigned u) {
    unsigned b = (u & 0x80000000u) ? (u ^ 0x80000000u) : ~u;
    return __uint_as_float(b);
}

// ---------------- GEMM: out = A(NNxK,lda) @ W^T, 128x128 tile, BK=64 ---------
// ONE barrier per K-iter; depth-2 A (3 x 16KB LDS bufs, gll16), ping-pong
// B regs. bcol-per-XCD swizzle: XCD x owns bcols {2x,2x+1} (MODE 0/1) so
// its W slice (512KB) stays L2-resident; row-panels stream with x2 reuse.
template<int MODE>
__global__ __launch_bounds__(256) void gemm(
    const __hip_bfloat16* __restrict__ A, int lda, int K,
    const int4* __restrict__ Wpk,
    const float* __restrict__ b0, const float* __restrict__ b1,
    __hip_bfloat16* __restrict__ obf, int ldo,
    unsigned* __restrict__ om) {
    __shared__ int4 sA4[3][1024];             // 48 KB: A staging; epilogue scratch
    __shared__ unsigned sm[128];
    __hip_bfloat16* lds = (__hip_bfloat16*)sA4;   // MODE 0 epilogue view
    float2* ldsZ = (float2*)sA4;                  // MODE 1 epilogue view (a,z)

    int bid = blockIdx.x;
    int xcd = bid & 7, kq = bid >> 3;
    int bcol, brow;
    if (MODE == 3) {             // 4 bcols: 2 XCDs per bcol, rows by parity
        bcol = xcd >> 1;
        brow = (kq << 1) | (xcd & 1);         // kq in [0,40)
    } else {                     // 16 bcols: 2 bcols per XCD (W L2-resident)
        bcol = (xcd << 1) | (kq & 1);
        brow = kq >> 1;                       // kq in [0,160)
    }
    int m0 = brow * 128, n0 = bcol * 128;

    int tid = threadIdx.x;
    int lane = tid & 63, wave = tid >> 6;
    int wr = wave >> 1, wc = wave & 1;
    int lm = lane & 15, quad = lane >> 4;
    int qx = (lm >> 1) & 3;                   // read-side bank swizzle

    const int KT32 = K >> 5;
    const int KT = K >> 6;       // BK64 tiles
    const int kend = KT;         // uniform (MODE 1 zero-structure handled per-j)
    const int4* Wp = Wpk + ((size_t)bcol * KT32 << 9) + wc * 256 + lane;

    // LDS per tile = two 32-k sub-slabs of 512 int4; bank-swizzled placement.
    auto issueA = [&](int kt, int p) {
        int k0 = kt << 6;
#pragma unroll
        for (int it = 0; it < 4; ++it) {
            int idx = it * 256 + tid;
            int s = idx >> 9, rem = idx & 511;
            int row = rem >> 2;
            int kc = (rem & 3) ^ ((row >> 1) & 3);    // src-side swizzle
            int gm = m0 + row; gm = gm < NN ? gm : NN - 1;
            gll16(A + (size_t)gm * lda + k0 + s * 32 + kc * 8,
                  (__hip_bfloat16*)(sA4[p]) + idx * 8);
        }
    };
    auto loadB = [&](int kt, int4 (&bb)[2][4]) {
#pragma unroll
        for (int s = 0; s < 2; ++s) {
            const int4* wn = Wp + ((size_t)(2 * kt + s) << 9);
#pragma unroll
            for (int j = 0; j < 4; ++j) bb[s][j] = wn[j * 64];
        }
    };

    f32x4 acc[4][4] = {};
    int4 bb0[2][4], bb1[2][4];
    issueA(0, 0);
    issueA(1, 1);
    loadB(0, bb0);

    auto ktbody = [&](int kt, int4 (&bbCur)[2][4], int4 (&bbNxt)[2][4]) {
        int p = kt % 3;
        if (kt + 1 < kend) loadB(kt + 1, bbNxt);
        __builtin_amdgcn_sched_barrier(0);
        if (kt + 1 < kend) __builtin_amdgcn_s_waitcnt(0x4F74);  // vmcnt(20): A(kt) retired
        else               __builtin_amdgcn_s_waitcnt(0x0F78);  // vmcnt(8) last iter
        __builtin_amdgcn_s_barrier();   // tile kt staged; all reads of buf
                                        // (kt-1)%3 complete (consumed pre-barrier)
        __builtin_amdgcn_sched_barrier(0);   // pins issueA below the barrier
        V16 a[4][2];
#pragma unroll
        for (int i = 0; i < 4; ++i)
#pragma unroll
            for (int s = 0; s < 2; ++s)
                a[i][s].i = sA4[p][s * 512 + (wr * 64 + i * 16 + lm) * 4 + (quad ^ qx)];
        if (kt + 2 < kend) issueA(kt + 2, (kt + 2) % 3);  // overwrites (kt-1)%3: safe
#pragma unroll
        for (int s = 0; s < 2; ++s)
#pragma unroll
            for (int i = 0; i < 4; ++i)
#pragma unroll
                for (int j = 0; j < 4; ++j) {
                    if (MODE == 1) {   // structural zeros: i_n no h-half, hn no inc-half
                        if (j == 2 && kt >= 8) continue;
                        if (j == 3 && kt < 8) continue;
                    }
                    V16 b; b.i = bbCur[s][j];
                    acc[i][j] = __builtin_amdgcn_mfma_f32_16x16x32_bf16(a[i][s].b, b.b, acc[i][j], 0, 0, 0);
                }
        __builtin_amdgcn_sched_barrier(0);
    };

    for (int k2 = 0; k2 < kend; k2 += 2) {       // kend always even (8 or 16)
        ktbody(k2, bb0, bb1);
        ktbody(k2 + 1, bb1, bb0);
    }

    if (MODE == 0) {
        // LDS-transpose epilogue, 2 row-phases of 64x128 bf16 (coalesced stores)
        __syncthreads();   // acc final; sA4 reusable as scratch
#pragma unroll
        for (int ph = 0; ph < 2; ++ph) {
            if (wr == ph) {
#pragma unroll
                for (int j = 0; j < 4; ++j) {
                    int c = wc * 64 + j * 16 + lm;
#pragma unroll
                    for (int i = 0; i < 4; ++i)
#pragma unroll
                        for (int r = 0; r < 4; ++r)
                            lds[(i * 16 + quad * 4 + r) * 128 + c] = __float2bfloat16(acc[i][j][r]);
                }
            }
            __syncthreads();
#pragma unroll
            for (int q = 0; q < 4; ++q) {
                int idx = q * 256 + tid;
                int rl = idx >> 4, c16 = idx & 15;
                int m = m0 + ph * 64 + rl;
                if (m < NN)
                    *(int4*)(obf + (size_t)m * ldo + n0 + c16 * 8) =
                        *(const int4*)(lds + rl * 128 + c16 * 8);
            }
            __syncthreads();
        }
    } else if (MODE == 1) {
        // fused GRU, split blend: epilogue computes a=(1-z)*n and z (fp32),
        // stores (a,z) pairs to LDS; writeout phase blends with COALESCED
        // bf16 h loads from the A operand's h-half. Same rounding as r16.
        __syncthreads();   // acc final; sA4 reusable as scratch
        int c32 = wc * 16 + lm;
        int hcol = bcol * 32 + c32;
        float rb = b0[hcol] + b1[hcol];
        float zb = b0[512 + hcol] + b1[512 + hcol];
        float ib = b0[1024 + hcol];
        float hb = b1[1024 + hcol];
#pragma unroll
        for (int i = 0; i < 4; ++i)
#pragma unroll
            for (int r = 0; r < 4; ++r) {
                int rloc = wr * 64 + i * 16 + quad * 4 + r;
                float rr = 1.f / (1.f + __expf(-(acc[i][0][r] + rb)));
                float zz = 1.f / (1.f + __expf(-(acc[i][1][r] + zb)));
                float nx = (acc[i][2][r] + ib) + rr * (acc[i][3][r] + hb);
                float n = 1.f - 2.f / (__expf(2.f * nx) + 1.f);
                ldsZ[rloc * 34 + c32] = make_float2((1.f - zz) * n, zz);
            }
        __syncthreads();
        // coalesced writeout: 128 rows x 32 cols bf16 (next step's A h-slot);
        // h read 8B/thread from A[m][512+bcol*32+c4..] (64B per 8 threads).
#pragma unroll
        for (int q = 0; q < 4; ++q) {
            int idx = q * 256 + tid;              // 1024 4-col units
            int rl = idx >> 3, c4 = (idx & 7) * 4;
            int m = m0 + rl;
            if (m < NN) {
                ulong1 hraw = *(const ulong1*)(A + (size_t)m * lda + 512 + bcol * 32 + c4);
                const __bf16* hb4 = (const __bf16*)&hraw;
                const float2* pz = ldsZ + rl * 34 + c4;
                __hip_bfloat16 ob[4];
#pragma unroll
                for (int e = 0; e < 4; ++e) {
                    float2 az = pz[e];
                    ob[e] = __float2bfloat16(az.x + az.y * bfl(hb4[e]));
                }
                *(ulong1*)(obf + (size_t)m * ldo + bcol * 32 + c4) = *(ulong1*)ob;
            }
        }
    } else {   // MODE 3: FC + column max
        if (tid < 128) sm[tid] = 0;
        __syncthreads();
#pragma unroll
        for (int j = 0; j < 4; ++j) {
            int c = wc * 64 + j * 16 + lm;
            float bias = b0[n0 + c];
            float mx = -INFINITY;
#pragma unroll
            for (int i = 0; i < 4; ++i) {
                int r0 = m0 + wr * 64 + i * 16 + quad * 4;
#pragma unroll
                for (int r = 0; r < 4; ++r) {
                    int m = r0 + r;
                    if (m < NN) mx = fmaxf(mx, acc[i][j][r] + bias);
                }
            }
            atomicMax(&sm[c], fenc(mx));
        }
        __syncthreads();
        if (tid < 128) atomicMax(&om[n0 + tid], sm[tid]);
    }
}

__global__ void writeout(const unsigned* __restrict__ om, float* __restrict__ o) {
    int c = threadIdx.x;
    o[c] = fdec(om[c]);
}

// ---------------- launch ----------------
extern "C" void kernel_launch(void* const* d_in, const int* in_sizes, int n_in,
                              void* d_out, int out_size, void* d_ws, size_t ws_size,
                              hipStream_t stream) {
    (void)in_sizes; (void)n_in; (void)out_size; (void)ws_size;
    const float* x    = (const float*)d_in[0];
    const int*   edges= (const int*)d_in[1];
    const float* Wmsg = (const float*)d_in[2];
    const float* bmsg = (const float*)d_in[3];
    const float* Wih  = (const float*)d_in[4];
    const float* Whh  = (const float*)d_in[5];
    const float* bih  = (const float*)d_in[6];
    const float* bhh  = (const float*)d_in[7];
    const float* fcW  = (const float*)d_in[8];
    const float* fcb  = (const float*)d_in[9];
    float* out = (float*)d_out;

    char* ws = (char*)d_ws;
    size_t off = 0;
    auto alloc = [&](size_t bytes) -> void* {
        void* p = ws + off; off += (bytes + 255) & ~(size_t)255; return p;
    };
    __hip_bfloat16* abA  = (__hip_bfloat16*)alloc((size_t)NN * 1024 * 2);   // 20.5 MB
    __hip_bfloat16* abB  = (__hip_bfloat16*)alloc((size_t)NN * 1024 * 2);   // 20.5 MB
    int*            bcnt = (int*)alloc((size_t)NN * NT * 4);                // 160 KB
    int*            bins = (int*)alloc((size_t)NN * NT * CAP * 4);          // 3.8 MB
    unsigned*       om   = (unsigned*)alloc(HD * 4);
    int4*           WmPK   = (int4*)alloc((size_t)2 * 131072 * 16);         // 4.2 MB
    int4*           WrznhPK= (int4*)alloc((size_t)2 * 262144 * 16);         // 8.4 MB
    int4*           WfPK   = (int4*)alloc((size_t)32768 * 16);              // 0.5 MB
    __hip_bfloat16* Msg  = (__hip_bfloat16*)alloc((size_t)NN * 2048 * 2);   // 41 MB
    // total ~99 MB

    hipMemsetAsync(bcnt, 0, (size_t)NN * NT * 4, stream);
    hipMemsetAsync(om, 0, HD * 4, stream);
    prep_all<<<1024 + 2048 + 128 + 5000 + 625, 256, 0, stream>>>(
        Wmsg, Wih, Whh, fcW, x, edges, WmPK, WrznhPK, WfPK, abA, bcnt, bins);

    for (int s = 0; s < 4; ++s) {
        int layer = s >> 1;
        __hip_bfloat16* cur = (s & 1) ? abB : abA;
        __hip_bfloat16* nxt = (s & 1) ? abA : abB;
        const int4* Wm = WmPK + (size_t)layer * 131072;
        const int4* Wz = WrznhPK + (size_t)layer * 262144;
        const float* bm = bmsg + (size_t)layer * 2048;
        const float* bi = bih + (size_t)layer * 1536;
        const float* bh = bhh + (size_t)layer * 1536;

        // Msg = h @ Wm^T  (out 2048, K=512)
        gemm<0><<<16 * GYROWS, 256, 0, stream>>>(cur + 512, 1024, 512, Wm,
            nullptr, nullptr, Msg, 2048, nullptr);
        // inc = gather(Msg) + cnt*bm -> cur[0:512]
        gather_msum<<<NN / 4, 256, 0, stream>>>(bins, bcnt, bm, Msg, cur);
        // fused GRU GEMM -> nxt h-slot (bf16)
        gemm<1><<<16 * GYROWS, 256, 0, stream>>>(cur, 1024, 1024, Wz,
            bi, bh, nxt + 512, 1024, nullptr);
    }
    // FC + column max (final h in abA h-slot after 4 steps)
    gemm<3><<<4 * GYROWS, 256, 0, stream>>>(abA + 512, 1024, 512, WfPK,
        fcb, nullptr, nullptr, 0, om);
    writeout<<<1, 512, 0, stream>>>(om, out);
}

// Round 11
// 558.933 us; speedup vs baseline: 1.1355x; 1.0547x over previous
//
#include <hip/hip_runtime.h>
#include <hip/hip_bf16.h>

// GGNN encoder: N=10000, H=512, T=4, E=40000, L=2 x 2 timesteps.
// fp32 inputs, fp32 output, bf16 MFMA internally.
//
// Per step (2 GEMM dispatches):
//   Msg  = h @ Wmsg_cat^T              (N x 2048, K=512)   [MODE 0]
//   inc  = gather-sum(Msg) + cnt*b     (N x 512)           [gather_msum]
//   h'   = fused GRU GEMM: [inc|h] @ Wrznh^T with GATE-INTERLEAVED packing
//          + split epilogue -> h (bf16)                    [MODE 1]
// Final: FC + column-max fused [MODE 3] -> writeout.
//
// r22: REVERT r21 swizzle (A-refetch x8 taxed gemm0; gemm1 win was -1us --
//   B-bandwidth theory falsified: dur invariant 56-58us across 2x traffic
//   changes). Single lever this round: OCCUPANCY 2 -> 3 waves/SIMD.
//   Evidence: occupancy pinned at ~17.5% (= 1.4 blocks/CU) across r14-r21.
//   gfx950 has a UNIFIED VGPR/AGPR file: 112 arch VGPR + 64 AGPR (acc[4][4])
//   = 176 regs/wave -> floor(512/176) = 2 waves/SIMD ceiling. With ~1.4
//   waves/SIMD there is no TLP; every latency is exposed serially -- which
//   is why all scheduling/caching levers bounced off the same wall.
//   Fix: __launch_bounds__(256,3) (cap 170 regs) + A-frag working set
//   a[4][2] -> a[4] per s-slab (saves 16 VGPR): ds_read s0 -> MFMA s0 ->
//   ds_read s1 -> MFMA s1. Total ~164 <= 170. LDS 3x48KB = 144 <= 160KB.
//
// Carried (r18 structure, 574us baseline): fused GRU epilogue
// (gate-interleaved WrznhPK, per-kt j-skip), split (a,z)-LDS blend with
// coalesced h reads (r17), no-h32 (r16), row-per-XCD swizzle, involutive
// LDS bank swizzle on A staging, BK=64, 3 rotating 16KB LDS bufs, depth-2
// ping-pong B regs, ONE barrier per K-iter (post-barrier issueA),
// vmcnt(20)/vmcnt(8) ladder.

#define NN 10000
#define HD 512
#define NT 4
#define NE 40000
#define CAP 24          // max edges per (target,type); P(Poisson(4)>24)~1e-14/bin
#define GYROWS 80       // padded to multiple of 8 for XCD swizzle (79 used)

typedef __bf16 bf16x8 __attribute__((ext_vector_type(8)));
typedef float f32x4 __attribute__((ext_vector_type(4)));
union V16 { int4 i; bf16x8 b; };

typedef __attribute__((address_space(1))) const unsigned int gu32;
typedef __attribute__((address_space(3))) unsigned int lu32;
__device__ __forceinline__ void gll16(const void* g, void* l) {
    __builtin_amdgcn_global_load_lds((gu32*)g, (lu32*)l, 16, 0, 0);
}

__device__ __forceinline__ float bfl(__bf16 v) { return (float)v; }

// pack 8 fp32 -> int4 of 8 bf16
__device__ __forceinline__ int4 cvt8(const float* __restrict__ s) {
    float4 v0 = *(const float4*)s, v1 = *(const float4*)(s + 4);
    V16 o;
    o.b[0] = (__bf16)v0.x; o.b[1] = (__bf16)v0.y; o.b[2] = (__bf16)v0.z; o.b[3] = (__bf16)v0.w;
    o.b[4] = (__bf16)v1.x; o.b[5] = (__bf16)v1.y; o.b[6] = (__bf16)v1.z; o.b[7] = (__bf16)v1.w;
    return o.i;
}

// Packed-W layout: [ct][kt32][s], s=0..511: wc=s>>8, j=(s>>6)&3, lane=s&63.
// Entry = int4 of W[pc][kt32*32+quad*8 .. +8], pc = ct*128+wc*64+j*16+(lane&15).
__device__ __forceinline__ void pk_decode(int rem, int KTbits, int& col, int& kk) {
    int ct = rem >> (KTbits + 9);
    int r2 = rem & ((1 << (KTbits + 9)) - 1);
    int kt = r2 >> 9, s = r2 & 511;
    int lane = s & 63;
    col = ct * 128 + ((s >> 8) << 6) + (((s >> 6) & 3) << 4) + (lane & 15);
    kk = kt * 32 + ((lane >> 4) & 3) * 8;
}

// ---------------- fused prep: pack weights, init, bins ----------------------
__global__ void prep_all(const float* __restrict__ Wmsg, const float* __restrict__ Wih,
                         const float* __restrict__ Whh, const float* __restrict__ fcW,
                         const float* __restrict__ x, const int* __restrict__ edges,
                         int4* __restrict__ WmPK, int4* __restrict__ WrznhPK,
                         int4* __restrict__ WfPK,
                         __hip_bfloat16* __restrict__ ab,
                         int* __restrict__ bcnt, int* __restrict__ bins) {
    int blk = blockIdx.x, tid = threadIdx.x;
    if (blk < 1024) {            // WmPK: per layer 16ct x 16kt x 512 = 131072
        int g = blk * 256 + tid;
        int l = g >> 17, rem = g & 131071;
        int col, kk; pk_decode(rem, 4, col, kk);
        WmPK[g] = cvt8(Wmsg + (size_t)l * 1048576 + (size_t)col * 512 + kk);
        return;
    }
    blk -= 1024;
    if (blk < 2048) {            // WrznhPK: per layer 16ct x 32kt x 512 = 262144
        // GATE-INTERLEAVED: packed col pc -> gate g=(pc>>4)&3,
        // hcol = (bcol*2 + wc)*16 + lm, bcol=pc>>7, wc=(pc>>6)&1, lm=pc&15.
        int g = blk * 256 + tid;
        int l = g >> 18, rem = g & 262143;
        int col, kk; pk_decode(rem, 5, col, kk);
        int gate = (col >> 4) & 3;
        int hcol = ((col >> 7) * 2 + ((col >> 6) & 1)) * 16 + (col & 15);
        int4 v = make_int4(0, 0, 0, 0);
        if (kk < 512) {
            // inc-half: W_ih rows {r:hcol, z:512+hcol, i_n:1024+hcol}; hn=0
            if (gate < 3) v = cvt8(Wih + (size_t)l * 786432 + (size_t)(gate * 512 + hcol) * 512 + kk);
        } else {
            // h-half: W_hh rows {r:hcol, z:512+hcol, hn:1024+hcol}; i_n=0
            if (gate < 2) v = cvt8(Whh + (size_t)l * 786432 + (size_t)(gate * 512 + hcol) * 512 + (kk - 512));
            else if (gate == 3) v = cvt8(Whh + (size_t)l * 786432 + (size_t)(1024 + hcol) * 512 + (kk - 512));
        }
        WrznhPK[g] = v;
        return;
    }
    blk -= 2048;
    if (blk < 128) {             // WfPK: 4ct x 16kt x 512 = 32768
        int g = blk * 256 + tid;
        int col, kk; pk_decode(g, 4, col, kk);
        WfPK[g] = cvt8(fcW + (size_t)col * 512 + kk);
        return;
    }
    blk -= 128;
    if (blk < 5000) {            // init: abA h-slot <- bf16(x)
        int i = blk * 1024 + tid * 4;
        float4 v = *(const float4*)(x + i);
        int m = i >> 9, c = i & 511;
        __hip_bfloat16 o[4] = {__float2bfloat16(v.x), __float2bfloat16(v.y),
                               __float2bfloat16(v.z), __float2bfloat16(v.w)};
        *(ulong1*)(ab + (size_t)m * 1024 + 512 + c) = *(ulong1*)o;
        return;
    }
    blk -= 5000;
    {                            // build_bins
        int i = blk * 256 + tid;
        if (i >= NT * NE) return;
        int src = edges[2 * i], tgt = edges[2 * i + 1];
        int t = i / NE;
        int b = tgt * NT + t;
        int pos = atomicAdd(&bcnt[b], 1);
        if (pos < CAP) bins[(size_t)b * CAP + pos] = src;
    }
}

// ---------------- gather: inc[n][c] = sum_t sum_src Msg[src][t*512+c] + cnt*bm
__global__ __launch_bounds__(256) void gather_msum(
    const int* __restrict__ bins, const int* __restrict__ bcnt,
    const float* __restrict__ bm, const __hip_bfloat16* __restrict__ Msg,
    __hip_bfloat16* __restrict__ inc) {
    int wave = threadIdx.x >> 6, lane = threadIdx.x & 63;
    int n = blockIdx.x * 4 + wave;
    int co = lane * 8;
    float acc[8] = {0, 0, 0, 0, 0, 0, 0, 0};
#pragma unroll
    for (int t = 0; t < NT; ++t) {
        int bi = n * NT + t;
        int cnt = bcnt[bi]; if (cnt > CAP) cnt = CAP;
        const int* bl = bins + (size_t)bi * CAP;
        for (int e = 0; e < cnt; ++e) {
            int src = bl[e];
            V16 v; v.i = *(const int4*)(Msg + (size_t)src * 2048 + t * 512 + co);
#pragma unroll
            for (int k = 0; k < 8; ++k) acc[k] += (float)v.b[k];
        }
        float4 b0 = *(const float4*)(bm + t * 512 + co);
        float4 b1 = *(const float4*)(bm + t * 512 + co + 4);
        float fc = (float)cnt;
        acc[0] += fc * b0.x; acc[1] += fc * b0.y; acc[2] += fc * b0.z; acc[3] += fc * b0.w;
        acc[4] += fc * b1.x; acc[5] += fc * b1.y; acc[6] += fc * b1.z; acc[7] += fc * b1.w;
    }
    V16 o;
#pragma unroll
    for (int k = 0; k < 8; ++k) o.b[k] = (__bf16)acc[k];
    *(int4*)(inc + (size_t)n * 1024 + co) = o.i;
}

// ---------------- monotone-uint float max encoding ----------------
__device__ __forceinline__ unsigned fenc(float f) {
    unsigned b = __float_as_uint(f);
    return b ^ (((int)b >> 31) | 0x80000000u);
}
__device__ __forceinline__ float fdec(unsigned u) {
    unsigned b = (u & 0x80000000u) ? (u ^ 0x80000000u) : ~u;
    return __uint_as_float(b);
}

// ---------------- GEMM: out = A(NNxK,lda) @ W^T, 128x128 tile, BK=64 ---------
// ONE barrier per K-iter; depth-2 A (3 x 16KB LDS bufs, gll16), ping-pong
// B regs. 3 waves/SIMD via __launch_bounds__(256,3) + per-s-slab A frags.
template<int MODE>
__global__ __launch_bounds__(256, 3) void gemm(
    const __hip_bfloat16* __restrict__ A, int lda, int K,
    const int4* __restrict__ Wpk,
    const float* __restrict__ b0, const float* __restrict__ b1,
    __hip_bfloat16* __restrict__ obf, int ldo,
    unsigned* __restrict__ om) {
    __shared__ int4 sA4[3][1024];             // 48 KB: A staging; epilogue scratch
    __shared__ unsigned sm[128];
    __hip_bfloat16* lds = (__hip_bfloat16*)sA4;   // MODE 0 epilogue view
    float2* ldsZ = (float2*)sA4;                  // MODE 1 epilogue view (a,z)

    const int NB = (MODE == 3) ? 4 : 16;      // bcols in grid
    int bid = blockIdx.x;
    int xcd = bid & 7, kq = bid >> 3;
    int bcol = kq % NB;
    int brow = xcd + 8 * (kq / NB);           // 0..79 exactly covered
    int m0 = brow * 128, n0 = bcol * 128;

    int tid = threadIdx.x;
    int lane = tid & 63, wave = tid >> 6;
    int wr = wave >> 1, wc = wave & 1;
    int lm = lane & 15, quad = lane >> 4;
    int qx = (lm >> 1) & 3;                   // read-side bank swizzle

    const int KT32 = K >> 5;
    const int KT = K >> 6;       // BK64 tiles
    const int kend = KT;         // uniform (MODE 1 zero-structure handled per-j)
    const int4* Wp = Wpk + ((size_t)bcol * KT32 << 9) + wc * 256 + lane;

    // LDS per tile = two 32-k sub-slabs of 512 int4; bank-swizzled placement.
    auto issueA = [&](int kt, int p) {
        int k0 = kt << 6;
#pragma unroll
        for (int it = 0; it < 4; ++it) {
            int idx = it * 256 + tid;
            int s = idx >> 9, rem = idx & 511;
            int row = rem >> 2;
            int kc = (rem & 3) ^ ((row >> 1) & 3);    // src-side swizzle
            int gm = m0 + row; gm = gm < NN ? gm : NN - 1;
            gll16(A + (size_t)gm * lda + k0 + s * 32 + kc * 8,
                  (__hip_bfloat16*)(sA4[p]) + idx * 8);
        }
    };
    auto loadB = [&](int kt, int4 (&bb)[2][4]) {
#pragma unroll
        for (int s = 0; s < 2; ++s) {
            const int4* wn = Wp + ((size_t)(2 * kt + s) << 9);
#pragma unroll
            for (int j = 0; j < 4; ++j) bb[s][j] = wn[j * 64];
        }
    };

    f32x4 acc[4][4] = {};
    int4 bb0[2][4], bb1[2][4];
    issueA(0, 0);
    issueA(1, 1);
    loadB(0, bb0);

    auto ktbody = [&](int kt, int4 (&bbCur)[2][4], int4 (&bbNxt)[2][4]) {
        int p = kt % 3;
        if (kt + 1 < kend) loadB(kt + 1, bbNxt);
        __builtin_amdgcn_sched_barrier(0);
        if (kt + 1 < kend) __builtin_amdgcn_s_waitcnt(0x4F74);  // vmcnt(20): A(kt) retired
        else               __builtin_amdgcn_s_waitcnt(0x0F78);  // vmcnt(8) last iter
        __builtin_amdgcn_s_barrier();   // tile kt staged; all reads of buf
                                        // (kt-1)%3 complete (consumed pre-barrier)
        __builtin_amdgcn_sched_barrier(0);   // pins issueA below the barrier
        if (kt + 2 < kend) issueA(kt + 2, (kt + 2) % 3);  // overwrites (kt-1)%3: safe
        // per-s-slab A fragments (16 VGPR working set, not 32)
#pragma unroll
        for (int s = 0; s < 2; ++s) {
            V16 a[4];
#pragma unroll
            for (int i = 0; i < 4; ++i)
                a[i].i = sA4[p][s * 512 + (wr * 64 + i * 16 + lm) * 4 + (quad ^ qx)];
#pragma unroll
            for (int i = 0; i < 4; ++i)
#pragma unroll
                for (int j = 0; j < 4; ++j) {
                    if (MODE == 1) {   // structural zeros: i_n no h-half, hn no inc-half
                        if (j == 2 && kt >= 8) continue;
                        if (j == 3 && kt < 8) continue;
                    }
                    V16 b; b.i = bbCur[s][j];
                    acc[i][j] = __builtin_amdgcn_mfma_f32_16x16x32_bf16(a[i].b, b.b, acc[i][j], 0, 0, 0);
                }
        }
        __builtin_amdgcn_sched_barrier(0);
    };

    for (int k2 = 0; k2 < kend; k2 += 2) {       // kend always even (8 or 16)
        ktbody(k2, bb0, bb1);
        ktbody(k2 + 1, bb1, bb0);
    }

    if (MODE == 0) {
        // LDS-transpose epilogue, 2 row-phases of 64x128 bf16 (coalesced stores)
        __syncthreads();   // acc final; sA4 reusable as scratch
#pragma unroll
        for (int ph = 0; ph < 2; ++ph) {
            if (wr == ph) {
#pragma unroll
                for (int j = 0; j < 4; ++j) {
                    int c = wc * 64 + j * 16 + lm;
#pragma unroll
                    for (int i = 0; i < 4; ++i)
#pragma unroll
                        for (int r = 0; r < 4; ++r)
                            lds[(i * 16 + quad * 4 + r) * 128 + c] = __float2bfloat16(acc[i][j][r]);
                }
            }
            __syncthreads();
#pragma unroll
            for (int q = 0; q < 4; ++q) {
                int idx = q * 256 + tid;
                int rl = idx >> 4, c16 = idx & 15;
                int m = m0 + ph * 64 + rl;
                if (m < NN)
                    *(int4*)(obf + (size_t)m * ldo + n0 + c16 * 8) =
                        *(const int4*)(lds + rl * 128 + c16 * 8);
            }
            __syncthreads();
        }
    } else if (MODE == 1) {
        // fused GRU, split blend: epilogue computes a=(1-z)*n and z (fp32),
        // stores (a,z) pairs to LDS; writeout phase blends with COALESCED
        // bf16 h loads from the A operand's h-half. Same rounding as r16.
        __syncthreads();   // acc final; sA4 reusable as scratch
        int c32 = wc * 16 + lm;
        int hcol = bcol * 32 + c32;
        float rb = b0[hcol] + b1[hcol];
        float zb = b0[512 + hcol] + b1[512 + hcol];
        float ib = b0[1024 + hcol];
        float hb = b1[1024 + hcol];
#pragma unroll
        for (int i = 0; i < 4; ++i)
#pragma unroll
            for (int r = 0; r < 4; ++r) {
                int rloc = wr * 64 + i * 16 + quad * 4 + r;
                float rr = 1.f / (1.f + __expf(-(acc[i][0][r] + rb)));
                float zz = 1.f / (1.f + __expf(-(acc[i][1][r] + zb)));
                float nx = (acc[i][2][r] + ib) + rr * (acc[i][3][r] + hb);
                float n = 1.f - 2.f / (__expf(2.f * nx) + 1.f);
                ldsZ[rloc * 34 + c32] = make_float2((1.f - zz) * n, zz);
            }
        __syncthreads();
        // coalesced writeout: 128 rows x 32 cols bf16 (next step's A h-slot);
        // h read 8B/thread from A[m][512+bcol*32+c4..] (64B per 8 threads).
#pragma unroll
        for (int q = 0; q < 4; ++q) {
            int idx = q * 256 + tid;              // 1024 4-col units
            int rl = idx >> 3, c4 = (idx & 7) * 4;
            int m = m0 + rl;
            if (m < NN) {
                ulong1 hraw = *(const ulong1*)(A + (size_t)m * lda + 512 + bcol * 32 + c4);
                const __bf16* hb4 = (const __bf16*)&hraw;
                const float2* pz = ldsZ + rl * 34 + c4;
                __hip_bfloat16 ob[4];
#pragma unroll
                for (int e = 0; e < 4; ++e) {
                    float2 az = pz[e];
                    ob[e] = __float2bfloat16(az.x + az.y * bfl(hb4[e]));
                }
                *(ulong1*)(obf + (size_t)m * ldo + bcol * 32 + c4) = *(ulong1*)ob;
            }
        }
    } else {   // MODE 3: FC + column max
        if (tid < 128) sm[tid] = 0;
        __syncthreads();
#pragma unroll
        for (int j = 0; j < 4; ++j) {
            int c = wc * 64 + j * 16 + lm;
            float bias = b0[n0 + c];
            float mx = -INFINITY;
#pragma unroll
            for (int i = 0; i < 4; ++i) {
                int r0 = m0 + wr * 64 + i * 16 + quad * 4;
#pragma unroll
                for (int r = 0; r < 4; ++r) {
                    int m = r0 + r;
                    if (m < NN) mx = fmaxf(mx, acc[i][j][r] + bias);
                }
            }
            atomicMax(&sm[c], fenc(mx));
        }
        __syncthreads();
        if (tid < 128) atomicMax(&om[n0 + tid], sm[tid]);
    }
}

__global__ void writeout(const unsigned* __restrict__ om, float* __restrict__ o) {
    int c = threadIdx.x;
    o[c] = fdec(om[c]);
}

// ---------------- launch ----------------
extern "C" void kernel_launch(void* const* d_in, const int* in_sizes, int n_in,
                              void* d_out, int out_size, void* d_ws, size_t ws_size,
                              hipStream_t stream) {
    (void)in_sizes; (void)n_in; (void)out_size; (void)ws_size;
    const float* x    = (const float*)d_in[0];
    const int*   edges= (const int*)d_in[1];
    const float* Wmsg = (const float*)d_in[2];
    const float* bmsg = (const float*)d_in[3];
    const float* Wih  = (const float*)d_in[4];
    const float* Whh  = (const float*)d_in[5];
    const float* bih  = (const float*)d_in[6];
    const float* bhh  = (const float*)d_in[7];
    const float* fcW  = (const float*)d_in[8];
    const float* fcb  = (const float*)d_in[9];
    float* out = (float*)d_out;

    char* ws = (char*)d_ws;
    size_t off = 0;
    auto alloc = [&](size_t bytes) -> void* {
        void* p = ws + off; off += (bytes + 255) & ~(size_t)255; return p;
    };
    __hip_bfloat16* abA  = (__hip_bfloat16*)alloc((size_t)NN * 1024 * 2);   // 20.5 MB
    __hip_bfloat16* abB  = (__hip_bfloat16*)alloc((size_t)NN * 1024 * 2);   // 20.5 MB
    int*            bcnt = (int*)alloc((size_t)NN * NT * 4);                // 160 KB
    int*            bins = (int*)alloc((size_t)NN * NT * CAP * 4);          // 3.8 MB
    unsigned*       om   = (unsigned*)alloc(HD * 4);
    int4*           WmPK   = (int4*)alloc((size_t)2 * 131072 * 16);         // 4.2 MB
    int4*           WrznhPK= (int4*)alloc((size_t)2 * 262144 * 16);         // 8.4 MB
    int4*           WfPK   = (int4*)alloc((size_t)32768 * 16);              // 0.5 MB
    __hip_bfloat16* Msg  = (__hip_bfloat16*)alloc((size_t)NN * 2048 * 2);   // 41 MB
    // total ~99 MB

    hipMemsetAsync(bcnt, 0, (size_t)NN * NT * 4, stream);
    hipMemsetAsync(om, 0, HD * 4, stream);
    prep_all<<<1024 + 2048 + 128 + 5000 + 625, 256, 0, stream>>>(
        Wmsg, Wih, Whh, fcW, x, edges, WmPK, WrznhPK, WfPK, abA, bcnt, bins);

    for (int s = 0; s < 4; ++s) {
        int layer = s >> 1;
        __hip_bfloat16* cur = (s & 1) ? abB : abA;
        __hip_bfloat16* nxt = (s & 1) ? abA : abB;
        const int4* Wm = WmPK + (size_t)layer * 131072;
        const int4* Wz = WrznhPK + (size_t)layer * 262144;
        const float* bm = bmsg + (size_t)layer * 2048;
        const float* bi = bih + (size_t)layer * 1536;
        const float* bh = bhh + (size_t)layer * 1536;

        // Msg = h @ Wm^T  (out 2048, K=512)
        gemm<0><<<16 * GYROWS, 256, 0, stream>>>(cur + 512, 1024, 512, Wm,
            nullptr, nullptr, Msg, 2048, nullptr);
        // inc = gather(Msg) + cnt*bm -> cur[0:512]
        gather_msum<<<NN / 4, 256, 0, stream>>>(bins, bcnt, bm, Msg, cur);
        // fused GRU GEMM -> nxt h-slot (bf16)
        gemm<1><<<16 * GYROWS, 256, 0, stream>>>(cur, 1024, 1024, Wz,
            bi, bh, nxt + 512, 1024, nullptr);
    }
    // FC + column max (final h in abA h-slot after 4 steps)
    gemm<3><<<4 * GYROWS, 256, 0, stream>>>(abA + 512, 1024, 512, WfPK,
        fcb, nullptr, nullptr, 0, om);
    writeout<<<1, 512, 0, stream>>>(om, out);
}